// Round 2
// baseline (733.621 us; speedup 1.0000x reference)
//
#include <hip/hip_runtime.h>

#define NE 50000      // N_ENT
#define NR 200        // N_REL
#define DD 128        // D
#define EF 300000     // E_FULL
#define EB 80000      // E_BATCH
#define NEG 0.2f

__device__ __forceinline__ float lrelu(float x){ return x >= 0.f ? x : NEG*x; }

// ---------- CSR build ----------
__global__ void k_count(const int* __restrict__ edge_data, int* __restrict__ cnt){
  int e = blockIdx.x*blockDim.x + threadIdx.x;
  if(e < EF) atomicAdd(&cnt[edge_data[2*EF + e]], 1);
}

// single-block scan: 4 elems/thread, wave-shfl scan + 16-wide LDS scan (few barriers)
__global__ void k_scan(const int* __restrict__ cnt, int* __restrict__ row_start){
  __shared__ int wsum[16];
  __shared__ int s_run;
  int tid = threadIdx.x;          // 1024
  int lane = tid & 63, wv = tid >> 6;
  if(tid==0) s_run = 0;
  __syncthreads();
  const int CH = 4096;
  const int nch = (NE + CH - 1)/CH;  // 13
  for(int c=0;c<nch;c++){
    int base = c*CH + tid*4;
    int v0 = base   < NE ? cnt[base]   : 0;
    int v1 = base+1 < NE ? cnt[base+1] : 0;
    int v2 = base+2 < NE ? cnt[base+2] : 0;
    int v3 = base+3 < NE ? cnt[base+3] : 0;
    int tsum = v0+v1+v2+v3;
    int x = tsum;                    // inclusive scan over threads in wave
    #pragma unroll
    for(int o=1;o<64;o<<=1){
      int y = __shfl_up(x, o);
      if(lane >= o) x += y;
    }
    if(lane==63) wsum[wv] = x;
    __syncthreads();
    if(wv==0 && lane<16){
      int w = wsum[lane];
      #pragma unroll
      for(int o=1;o<16;o<<=1){
        int y = __shfl_up(w, o);
        if(lane>=o) w += y;
      }
      wsum[lane] = w;                // inclusive over waves
    }
    __syncthreads();
    int woff = (wv>0) ? wsum[wv-1] : 0;
    int excl = s_run + woff + x - tsum;
    if(base   < NE) row_start[base]   = excl;
    if(base+1 < NE) row_start[base+1] = excl + v0;
    if(base+2 < NE) row_start[base+2] = excl + v0+v1;
    if(base+3 < NE) row_start[base+3] = excl + v0+v1+v2;
    __syncthreads();
    if(tid==1023) s_run += wsum[15];
    __syncthreads();
  }
  if(tid==0) row_start[NE] = s_run;
}

__global__ void k_fill(const int* __restrict__ edge_data, const int* __restrict__ row_start,
                       int* __restrict__ cnt, int* __restrict__ src_s, int* __restrict__ rel_s){
  int e = blockIdx.x*blockDim.x + threadIdx.x;
  if(e < EF){
    int s = edge_data[e], r = edge_data[EF+e], d = edge_data[2*EF+e];
    int pos = row_start[d] + atomicAdd(&cnt[d], 1);
    src_s[pos] = s; rel_s[pos] = r;
  }
}

// ---------- tiny precomputes ----------
// vecE_l[d][h] = sum_c We_l[d][h*C+c] * att_e_l[h][c]
__global__ void k_vecE(const float* __restrict__ We1, const float* __restrict__ ae1,
                       const float* __restrict__ We2, const float* __restrict__ ae2,
                       float* __restrict__ vecE1, float* __restrict__ vecE2){
  int t = threadIdx.x;           // 256
  int d = t>>1, h = t&1;
  float s1 = 0.f;
  for(int c=0;c<64;c++)  s1 += We1[d*128 + h*64  + c]*ae1[h*64  + c];
  vecE1[d*2+h] = s1;
  float s2 = 0.f;
  for(int c=0;c<128;c++) s2 += We2[d*256 + h*128 + c]*ae2[h*128 + c];
  vecE2[d*2+h] = s2;
}

// aE_l[r][h] = rel_emb[r] . vecE_l[:,h]
__global__ void k_aE(const float* __restrict__ rel_emb, const float* __restrict__ vecE1,
                     const float* __restrict__ vecE2, float* __restrict__ aE1, float* __restrict__ aE2){
  int r = blockIdx.x, l = threadIdx.x;  // 64 threads
  float re0 = rel_emb[r*128 + l], re1 = rel_emb[r*128 + 64 + l];
  float a10 = re0*vecE1[l*2+0] + re1*vecE1[(64+l)*2+0];
  float a11 = re0*vecE1[l*2+1] + re1*vecE1[(64+l)*2+1];
  float a20 = re0*vecE2[l*2+0] + re1*vecE2[(64+l)*2+0];
  float a21 = re0*vecE2[l*2+1] + re1*vecE2[(64+l)*2+1];
  for(int o=32;o;o>>=1){
    a10 += __shfl_xor(a10,o); a11 += __shfl_xor(a11,o);
    a20 += __shfl_xor(a20,o); a21 += __shfl_xor(a21,o);
  }
  if(l==0){ aE1[r*2]=a10; aE1[r*2+1]=a11; aE2[r*2]=a20; aE2[r*2+1]=a21; }
}

__global__ void k_tr(const float* __restrict__ A, float* __restrict__ At, int R, int C){
  int t = blockIdx.x*blockDim.x + threadIdx.x;
  if(t < R*C){ int r = t / C, c = t % C; At[c*R + r] = A[t]; }
}

// ---------- GEMM: Y[N,O] = X[N,128] @ W[128,O], row-major, 64x64 tile ----------
template<int O>
__global__ __launch_bounds__(256) void k_gemm(const float* __restrict__ X, const float* __restrict__ W,
                                              float* __restrict__ Y, int Nrows){
  __shared__ float As[64][128];   // XOR-swizzled: logical col c stored at c ^ (((row>>2)&3)<<2)
  __shared__ float Bs[128][64];
  int n0 = blockIdx.x*64;
  int cb = blockIdx.y*64;
  int t  = threadIdx.x;
  #pragma unroll
  for(int i=0;i<8;i++){
    int flat = i*1024 + t*4;
    int row = flat>>7, col = flat&127;
    float4 v = make_float4(0.f,0.f,0.f,0.f);
    if(n0+row < Nrows) v = *reinterpret_cast<const float4*>(&X[(size_t)(n0+row)*128 + col]);
    int cs = col ^ (((row>>2)&3)<<2);
    *reinterpret_cast<float4*>(&As[row][cs]) = v;
  }
  #pragma unroll
  for(int i=0;i<8;i++){
    int flat = i*1024 + t*4;
    int d = flat>>6, c = flat&63;
    float4 v = *reinterpret_cast<const float4*>(&W[(size_t)d*O + cb + c]);
    *reinterpret_cast<float4*>(&Bs[d][c]) = v;
  }
  __syncthreads();
  int tx = t&15, ty = t>>4;
  float acc[4][4] = {};
  #pragma unroll 8
  for(int d4=0; d4<32; d4++){
    float4 a[4], b[4];
    #pragma unroll
    for(int i=0;i<4;i++)   // row = ty*4+i -> row>>2 == ty, swizzle key = (ty&3)<<2
      a[i] = *reinterpret_cast<const float4*>(&As[ty*4+i][(d4*4) ^ ((ty&3)<<2)]);
    #pragma unroll
    for(int dd=0;dd<4;dd++)
      b[dd] = *reinterpret_cast<const float4*>(&Bs[d4*4+dd][tx*4]);
    #pragma unroll
    for(int dd=0;dd<4;dd++){
      const float* bp = reinterpret_cast<const float*>(&b[dd]);
      #pragma unroll
      for(int i=0;i<4;i++){
        float av = reinterpret_cast<const float*>(&a[i])[dd];
        #pragma unroll
        for(int j=0;j<4;j++) acc[i][j] += av * bp[j];
      }
    }
  }
  #pragma unroll
  for(int i=0;i<4;i++){
    int n = n0 + ty*4 + i;
    if(n < Nrows){
      float4 v = make_float4(acc[i][0],acc[i][1],acc[i][2],acc[i][3]);
      *reinterpret_cast<float4*>(&Y[(size_t)n*O + cb + tx*4]) = v;
    }
  }
}

// ---------- per-node attention scalars ----------
template<int C>
__global__ void k_attn(const float* __restrict__ xt, const float* __restrict__ att_s,
                       const float* __restrict__ att_d, float* __restrict__ asrc,
                       float* __restrict__ adst){
  int wv = threadIdx.x>>6, l = threadIdx.x&63;
  int n = blockIdx.x*4 + wv;
  if(n >= NE) return;
  const float* row = xt + (size_t)n*2*C;
  float s0,s1,d0,d1;
  if(C==64){
    float v0=row[l], v1=row[64+l];
    s0 = v0*att_s[l];    s1 = v1*att_s[64+l];
    d0 = v0*att_d[l];    d1 = v1*att_d[64+l];
  } else {
    float v0=row[l], v1=row[64+l], v2=row[128+l], v3=row[192+l];
    s0 = v0*att_s[l] + v1*att_s[64+l];
    s1 = v2*att_s[128+l] + v3*att_s[192+l];
    d0 = v0*att_d[l] + v1*att_d[64+l];
    d1 = v2*att_d[128+l] + v3*att_d[192+l];
  }
  for(int o=32;o;o>>=1){
    s0+=__shfl_xor(s0,o); s1+=__shfl_xor(s1,o);
    d0+=__shfl_xor(d0,o); d1+=__shfl_xor(d1,o);
  }
  if(l==0){ asrc[n*2]=s0; asrc[n*2+1]=s1; adst[n*2]=d0; adst[n*2+1]=d1; }
}

// ---------- gather-based GAT aggregation, online softmax, one wave per node ----------
template<int C, bool LK>
__global__ __launch_bounds__(256) void k_agg(const float* __restrict__ xt,
    const float* __restrict__ asrc, const float* __restrict__ adst,
    const float* __restrict__ aE, const int* __restrict__ row_start,
    const int* __restrict__ src_s, const int* __restrict__ rel_s,
    const float* __restrict__ bias, float* __restrict__ outp){
  constexpr int HC = 2*C;
  constexpr int NJ = HC/64;
  int wv = threadIdx.x>>6, l = threadIdx.x&63;
  int n = blockIdx.x*4 + wv;
  if(n >= NE) return;
  int b = row_start[n], e = row_start[n+1];
  int deg = e - b;
  float2 ad = *reinterpret_cast<const float2*>(&adst[n*2]);
  // self-loop edge logit uses mean of incoming aE (PyG fill_value='mean')
  float sE0=0.f, sE1=0.f;
  for(int i=b;i<e;i++){
    float2 a = *reinterpret_cast<const float2*>(&aE[rel_s[i]*2]);
    sE0 += a.x; sE1 += a.y;
  }
  float invdeg = 1.f/fmaxf((float)deg, 1.f);
  float2 asn = *reinterpret_cast<const float2*>(&asrc[n*2]);
  float m0 = lrelu(asn.x + ad.x + sE0*invdeg);
  float m1 = lrelu(asn.y + ad.y + sE1*invdeg);
  float den0=1.f, den1=1.f;
  float acc[NJ];
  #pragma unroll
  for(int j=0;j<NJ;j++) acc[j] = xt[(size_t)n*HC + j*64 + l];
  for(int i=b;i<e;i++){
    int s = src_s[i], r = rel_s[i];
    float2 as = *reinterpret_cast<const float2*>(&asrc[s*2]);
    float2 ae = *reinterpret_cast<const float2*>(&aE[r*2]);
    float l0 = lrelu(as.x + ad.x + ae.x);
    float l1 = lrelu(as.y + ad.y + ae.y);
    float nm0 = fmaxf(m0,l0), nm1 = fmaxf(m1,l1);
    float sc0 = __expf(m0-nm0), sc1 = __expf(m1-nm1);
    float w0  = __expf(l0-nm0), w1  = __expf(l1-nm1);
    den0 = den0*sc0 + w0; den1 = den1*sc1 + w1;
    m0 = nm0; m1 = nm1;
    #pragma unroll
    for(int j=0;j<NJ;j++){
      float sc = ((j*64)/C == 0) ? sc0 : sc1;
      float w  = ((j*64)/C == 0) ? w0  : w1;
      acc[j] = acc[j]*sc + w * xt[(size_t)s*HC + j*64 + l];
    }
  }
  float i0 = 1.f/(den0 + 1e-16f), i1 = 1.f/(den1 + 1e-16f);
  #pragma unroll
  for(int j=0;j<NJ;j++){
    int comp = j*64 + l;
    float v = acc[j] * (((j*64)/C == 0) ? i0 : i1) + bias[comp];
    if(LK) v = lrelu(v);
    outp[(size_t)n*HC + comp] = v;
  }
}

// ---------- head-mean + skip + L2 normalize ----------
__global__ void k_combine(const float* __restrict__ out2, const float* __restrict__ skip,
                          float* __restrict__ xf){
  int wv = threadIdx.x>>6, l = threadIdx.x&63;
  int n = blockIdx.x*4 + wv;
  if(n >= NE) return;
  float v0 = 0.5f*(out2[(size_t)n*256 + l]      + out2[(size_t)n*256 + 128 + l]) + skip[(size_t)n*128 + l];
  float v1 = 0.5f*(out2[(size_t)n*256 + 64 + l] + out2[(size_t)n*256 + 192 + l]) + skip[(size_t)n*128 + 64 + l];
  float ss = v0*v0 + v1*v1;
  for(int o=32;o;o>>=1) ss += __shfl_xor(ss,o);
  float inv = 1.f/fmaxf(sqrtf(ss), 1e-12f);
  xf[(size_t)n*128 + l]      = v0*inv;
  xf[(size_t)n*128 + 64 + l] = v1*inv;
}

__global__ void k_gather(const int* __restrict__ ei, const float* __restrict__ xf,
                         float* __restrict__ out){
  int wv = threadIdx.x>>6, l = threadIdx.x&63;
  int e = blockIdx.x*4 + wv;
  if(e >= EB) return;
  int i0 = ei[e], i1 = ei[EB + e];
  out[(size_t)e*128 + l]                     = xf[(size_t)i0*128 + l];
  out[(size_t)e*128 + 64 + l]                = xf[(size_t)i0*128 + 64 + l];
  out[(size_t)EB*128 + (size_t)e*128 + l]    = xf[(size_t)i1*128 + l];
  out[(size_t)EB*128 + (size_t)e*128 + 64+l] = xf[(size_t)i1*128 + 64 + l];
}

// ---------- edge_attr @ W_r.T via sparsity (exact: zero terms contribute exact 0) ----------
__global__ void k_attr(const float* __restrict__ ea, const float* __restrict__ Wrt,
                       float* __restrict__ out){
  int wv = threadIdx.x>>6, l = threadIdx.x&63;
  int e = blockIdx.x*4 + wv;
  if(e >= EB) return;
  const float* row = ea + (size_t)e*NR;
  float acc0=0.f, acc1=0.f;
  #pragma unroll
  for(int ch=0; ch<4; ch++){
    int idx = ch*64 + l;
    float v = (idx < NR) ? row[idx] : 0.f;
    unsigned long long mask = __ballot(v != 0.f);
    while(mask){
      int bit = __builtin_ctzll(mask);
      mask &= mask - 1;
      int r = ch*64 + bit;
      float vv = __shfl(v, bit);
      acc0 += vv * Wrt[r*128 + l];
      acc1 += vv * Wrt[r*128 + 64 + l];
    }
  }
  out[(size_t)e*128 + l]      = acc0;
  out[(size_t)e*128 + 64 + l] = acc1;
}

extern "C" void kernel_launch(void* const* d_in, const int* in_sizes, int n_in,
                              void* d_out, int out_size, void* d_ws, size_t ws_size,
                              hipStream_t stream){
  const int*   edge_index = (const int*)  d_in[0];
  const float* edge_attr  = (const float*)d_in[1];
  const int*   edge_data  = (const int*)  d_in[2];
  const float* ent_emb    = (const float*)d_in[3];
  const float* rel_emb    = (const float*)d_in[4];
  const float* W1     = (const float*)d_in[5];
  const float* We1    = (const float*)d_in[6];
  const float* att_s1 = (const float*)d_in[7];
  const float* att_d1 = (const float*)d_in[8];
  const float* att_e1 = (const float*)d_in[9];
  const float* b1     = (const float*)d_in[10];
  const float* W2     = (const float*)d_in[11];
  const float* We2    = (const float*)d_in[12];
  const float* att_s2 = (const float*)d_in[13];
  const float* att_d2 = (const float*)d_in[14];
  const float* att_e2 = (const float*)d_in[15];
  const float* b2     = (const float*)d_in[16];
  const float* W_skip = (const float*)d_in[17];
  const float* W_r    = (const float*)d_in[18];
  float* out = (float*)d_out;

  char* ws = (char*)d_ws;
  size_t off = 0;
  auto alloc = [&](size_t bytes){ void* p = ws + off; off += (bytes + 255) & ~(size_t)255; return p; };
  int*   cnt       = (int*)  alloc((size_t)NE*4);
  int*   row_start = (int*)  alloc((size_t)(NE+1)*4);
  int*   src_s     = (int*)  alloc((size_t)EF*4);
  int*   rel_s     = (int*)  alloc((size_t)EF*4);
  float* vecE1     = (float*)alloc(128*2*4);
  float* vecE2     = (float*)alloc(128*2*4);
  float* aE1       = (float*)alloc(NR*2*4);
  float* aE2       = (float*)alloc(NR*2*4);
  float* asrc1     = (float*)alloc((size_t)NE*2*4);
  float* adst1     = (float*)alloc((size_t)NE*2*4);
  float* asrc2     = (float*)alloc((size_t)NE*2*4);
  float* adst2     = (float*)alloc((size_t)NE*2*4);
  float* Wt        = (float*)alloc(128*128*4);
  float* Wrt       = (float*)alloc(NR*128*4);
  float* xt1       = (float*)alloc((size_t)NE*128*4);  // reused as `skip` after agg1
  float* h1        = (float*)alloc((size_t)NE*128*4);  // reused as `x_final` after gemm2
  float* skip = xt1;
  float* xf   = h1;
  // d_out doubles as scratch for the big [N,256] buffers; both dead before final writes.
  float* xt2  = out;                        // [NE*256] = 12.8M floats
  float* out2 = out + (size_t)NE*256;       // next 12.8M floats

  hipMemsetAsync(cnt, 0, (size_t)NE*4, stream);
  k_count<<<(EF+255)/256, 256, 0, stream>>>(edge_data, cnt);
  k_scan<<<1, 1024, 0, stream>>>(cnt, row_start);
  hipMemsetAsync(cnt, 0, (size_t)NE*4, stream);
  k_fill<<<(EF+255)/256, 256, 0, stream>>>(edge_data, row_start, cnt, src_s, rel_s);
  k_vecE<<<1, 256, 0, stream>>>(We1, att_e1, We2, att_e2, vecE1, vecE2);
  k_aE<<<NR, 64, 0, stream>>>(rel_emb, vecE1, vecE2, aE1, aE2);

  dim3 g1((NE+63)/64, 2);  // O=128
  dim3 g2((NE+63)/64, 4);  // O=256
  k_gemm<128><<<g1, 256, 0, stream>>>(ent_emb, W1, xt1, NE);
  k_attn<64><<<(NE+3)/4, 256, 0, stream>>>(xt1, att_s1, att_d1, asrc1, adst1);
  k_agg<64, true><<<(NE+3)/4, 256, 0, stream>>>(xt1, asrc1, adst1, aE1, row_start, src_s, rel_s, b1, h1);

  k_gemm<256><<<g2, 256, 0, stream>>>(h1, W2, xt2, NE);
  k_attn<128><<<(NE+3)/4, 256, 0, stream>>>(xt2, att_s2, att_d2, asrc2, adst2);
  k_agg<128, false><<<(NE+3)/4, 256, 0, stream>>>(xt2, asrc2, adst2, aE2, row_start, src_s, rel_s, b2, out2);

  k_tr<<<(128*128+255)/256, 256, 0, stream>>>(W_skip, Wt, 128, 128);
  k_gemm<128><<<g1, 256, 0, stream>>>(ent_emb, Wt, skip, NE);
  k_combine<<<(NE+3)/4, 256, 0, stream>>>(out2, skip, xf);

  k_tr<<<(128*NR+255)/256, 256, 0, stream>>>(W_r, Wrt, 128, NR);
  k_gather<<<(EB+3)/4, 256, 0, stream>>>(edge_index, xf, out);
  k_attr<<<(EB+3)/4, 256, 0, stream>>>(edge_attr, Wrt, out + (size_t)2*EB*128);
}

// Round 3
// 574.982 us; speedup vs baseline: 1.2759x; 1.2759x over previous
//
#include <hip/hip_runtime.h>

#define NE 50000      // N_ENT
#define NR 200        // N_REL
#define DD 128        // D
#define EF 300000     // E_FULL
#define EB 80000      // E_BATCH
#define NEG 0.2f

typedef unsigned short u16;
typedef u16 u16x8 __attribute__((ext_vector_type(8)));
typedef __bf16 bf16x8 __attribute__((ext_vector_type(8)));
typedef float f32x4 __attribute__((ext_vector_type(4)));

__device__ __forceinline__ float lrelu(float x){ return x >= 0.f ? x : NEG*x; }
__device__ __forceinline__ u16 f2bf(float f){
  unsigned u = __float_as_uint(f);
  u = (u + 0x7FFFu + ((u >> 16) & 1u)) >> 16;   // RNE
  return (u16)u;
}
__device__ __forceinline__ float bf2f(u16 u){ return __uint_as_float(((unsigned)u) << 16); }

// ---------- CSR build ----------
__global__ void k_count(const int* __restrict__ edge_data, int* __restrict__ cnt){
  int e = blockIdx.x*blockDim.x + threadIdx.x;
  if(e < EF) atomicAdd(&cnt[edge_data[2*EF + e]], 1);
}

// single-block scan: 4 elems/thread, wave-shfl scan + 16-wide LDS scan
__global__ void k_scan(const int* __restrict__ cnt, int* __restrict__ row_start){
  __shared__ int wsum[16];
  __shared__ int s_run;
  int tid = threadIdx.x;          // 1024
  int lane = tid & 63, wv = tid >> 6;
  if(tid==0) s_run = 0;
  __syncthreads();
  const int CH = 4096;
  const int nch = (NE + CH - 1)/CH;  // 13
  for(int c=0;c<nch;c++){
    int base = c*CH + tid*4;
    int v0 = base   < NE ? cnt[base]   : 0;
    int v1 = base+1 < NE ? cnt[base+1] : 0;
    int v2 = base+2 < NE ? cnt[base+2] : 0;
    int v3 = base+3 < NE ? cnt[base+3] : 0;
    int tsum = v0+v1+v2+v3;
    int x = tsum;
    #pragma unroll
    for(int o=1;o<64;o<<=1){
      int y = __shfl_up(x, o);
      if(lane >= o) x += y;
    }
    if(lane==63) wsum[wv] = x;
    __syncthreads();
    if(wv==0 && lane<16){
      int w = wsum[lane];
      #pragma unroll
      for(int o=1;o<16;o<<=1){
        int y = __shfl_up(w, o);
        if(lane>=o) w += y;
      }
      wsum[lane] = w;
    }
    __syncthreads();
    int woff = (wv>0) ? wsum[wv-1] : 0;
    int excl = s_run + woff + x - tsum;
    if(base   < NE) row_start[base]   = excl;
    if(base+1 < NE) row_start[base+1] = excl + v0;
    if(base+2 < NE) row_start[base+2] = excl + v0+v1;
    if(base+3 < NE) row_start[base+3] = excl + v0+v1+v2;
    __syncthreads();
    if(tid==1023) s_run += wsum[15];
    __syncthreads();
  }
  if(tid==0) row_start[NE] = s_run;
}

__global__ void k_fill(const int* __restrict__ edge_data, const int* __restrict__ row_start,
                       int* __restrict__ cnt, int* __restrict__ src_s, int* __restrict__ rel_s){
  int e = blockIdx.x*blockDim.x + threadIdx.x;
  if(e < EF){
    int s = edge_data[e], r = edge_data[EF+e], d = edge_data[2*EF+e];
    int pos = row_start[d] + atomicAdd(&cnt[d], 1);
    src_s[pos] = s; rel_s[pos] = r;
  }
}

// ---------- tiny precomputes ----------
__global__ void k_vecE(const float* __restrict__ We1, const float* __restrict__ ae1,
                       const float* __restrict__ We2, const float* __restrict__ ae2,
                       float* __restrict__ vecE1, float* __restrict__ vecE2){
  int t = threadIdx.x;           // 256
  int d = t>>1, h = t&1;
  float s1 = 0.f;
  for(int c=0;c<64;c++)  s1 += We1[d*128 + h*64  + c]*ae1[h*64  + c];
  vecE1[d*2+h] = s1;
  float s2 = 0.f;
  for(int c=0;c<128;c++) s2 += We2[d*256 + h*128 + c]*ae2[h*128 + c];
  vecE2[d*2+h] = s2;
}

__global__ void k_aE(const float* __restrict__ rel_emb, const float* __restrict__ vecE1,
                     const float* __restrict__ vecE2, float* __restrict__ aE1, float* __restrict__ aE2){
  int r = blockIdx.x, l = threadIdx.x;  // 64 threads
  float re0 = rel_emb[r*128 + l], re1 = rel_emb[r*128 + 64 + l];
  float a10 = re0*vecE1[l*2+0] + re1*vecE1[(64+l)*2+0];
  float a11 = re0*vecE1[l*2+1] + re1*vecE1[(64+l)*2+1];
  float a20 = re0*vecE2[l*2+0] + re1*vecE2[(64+l)*2+0];
  float a21 = re0*vecE2[l*2+1] + re1*vecE2[(64+l)*2+1];
  for(int o=32;o;o>>=1){
    a10 += __shfl_xor(a10,o); a11 += __shfl_xor(a11,o);
    a20 += __shfl_xor(a20,o); a21 += __shfl_xor(a21,o);
  }
  if(l==0){ aE1[r*2]=a10; aE1[r*2+1]=a11; aE2[r*2]=a20; aE2[r*2+1]=a21; }
}

__global__ void k_tr(const float* __restrict__ A, float* __restrict__ At, int R, int C){
  int t = blockIdx.x*blockDim.x + threadIdx.x;
  if(t < R*C){ int r = t / C, c = t % C; At[c*R + r] = A[t]; }
}

// builds WT1s[256][128] = [W1^T ; W_skip] bf16, WT2[256][128] = W2^T bf16
__global__ void k_prep(const float* __restrict__ W1, const float* __restrict__ Wsk,
                       const float* __restrict__ W2, u16* __restrict__ WT1s, u16* __restrict__ WT2){
  int r = blockIdx.x, k = threadIdx.x;   // 512 x 128
  if(r < 128)       WT1s[r*128+k] = f2bf(W1[k*128 + r]);
  else if(r < 256)  WT1s[r*128+k] = f2bf(Wsk[(r-128)*128 + k]);
  else              WT2[(r-256)*128+k] = f2bf(W2[k*256 + (r-256)]);
}

// ---------- MFMA GEMM: Y[N,O=256] = X[N,128] @ Wcat, Wcat given transposed bf16 WT[256][128]
// XBF: X is bf16[N][128] else f32. SPLIT: cols 0..127 -> Y0 f32 (stride 128),
// cols 128..255 -> Yb bf16 (stride 128); else all 256 cols -> Y0 f32 (stride 256).
template<bool XBF, bool SPLIT>
__global__ __launch_bounds__(256) void k_mgemm(const void* __restrict__ Xv,
    const u16* __restrict__ WT, float* __restrict__ Y0, u16* __restrict__ Yb, int Nrows){
  __shared__ u16 As[64*128];   // [row][k], 16B chunk kc stored at kc ^ (row&7)
  __shared__ u16 Bs[64*128];   // [col][k], same swizzle
  int n0 = blockIdx.x*64;
  int cb = blockIdx.y*64;
  int t  = threadIdx.x;
  // ---- stage A (64 rows x 128 k), convert to bf16 if needed ----
  #pragma unroll
  for(int i=0;i<4;i++){
    int c = i*256 + t;            // chunk 0..1023
    int row = c >> 4, kc = c & 15;
    u16x8 pk;
    if(XBF){
      const u16* Xb = (const u16*)Xv;
      if(n0+row < Nrows) pk = *reinterpret_cast<const u16x8*>(&Xb[(size_t)(n0+row)*128 + kc*8]);
      else               pk = (u16x8)(u16)0;
    } else {
      const float* Xf = (const float*)Xv;
      float4 v0 = make_float4(0,0,0,0), v1 = v0;
      if(n0+row < Nrows){
        const float4* p = reinterpret_cast<const float4*>(&Xf[(size_t)(n0+row)*128 + kc*8]);
        v0 = p[0]; v1 = p[1];
      }
      pk[0]=f2bf(v0.x); pk[1]=f2bf(v0.y); pk[2]=f2bf(v0.z); pk[3]=f2bf(v0.w);
      pk[4]=f2bf(v1.x); pk[5]=f2bf(v1.y); pk[6]=f2bf(v1.z); pk[7]=f2bf(v1.w);
    }
    *reinterpret_cast<u16x8*>(&As[row*128 + ((kc ^ (row&7))<<3)]) = pk;
  }
  // ---- stage B: WT rows cb..cb+63 ----
  #pragma unroll
  for(int i=0;i<4;i++){
    int c = i*256 + t;
    int row = c >> 4, kc = c & 15;
    u16x8 pk = *reinterpret_cast<const u16x8*>(&WT[(size_t)(cb+row)*128 + kc*8]);
    *reinterpret_cast<u16x8*>(&Bs[row*128 + ((kc ^ (row&7))<<3)]) = pk;
  }
  __syncthreads();
  // ---- MFMA: wave w -> (wr,wc) 32x32 sub-tile, 2x2 frags of 16x16, K-loop x4 ----
  int l = t & 63, w = t >> 6;
  int wr = w >> 1, wc = w & 1;
  int lr = l & 15, kg = l >> 4;
  f32x4 acc[2][2] = {};
  const bf16x8* asp = reinterpret_cast<const bf16x8*>(As);
  const bf16x8* bsp = reinterpret_cast<const bf16x8*>(Bs);
  #pragma unroll
  for(int kk=0; kk<4; kk++){
    bf16x8 a[2], b[2];
    #pragma unroll
    for(int m=0;m<2;m++){
      int fr = wr*32 + m*16 + lr;
      a[m] = asp[fr*16 + ((kk*4 + kg) ^ (fr&7))];
    }
    #pragma unroll
    for(int n=0;n<2;n++){
      int fc = wc*32 + n*16 + lr;
      b[n] = bsp[fc*16 + ((kk*4 + kg) ^ (fc&7))];
    }
    #pragma unroll
    for(int m=0;m<2;m++)
      #pragma unroll
      for(int n=0;n<2;n++)
        acc[m][n] = __builtin_amdgcn_mfma_f32_16x16x32_bf16(a[m], b[n], acc[m][n], 0, 0, 0);
  }
  // ---- epilogue: D lane map col=l&15, row=(l>>4)*4+r ----
  #pragma unroll
  for(int m=0;m<2;m++){
    #pragma unroll
    for(int r=0;r<4;r++){
      int grow = n0 + wr*32 + m*16 + kg*4 + r;
      if(grow >= Nrows) continue;
      #pragma unroll
      for(int n=0;n<2;n++){
        int gcol = cb + wc*32 + n*16 + lr;
        float v = acc[m][n][r];
        if(SPLIT){
          if(cb >= 128) Yb[(size_t)grow*128 + (gcol-128)] = f2bf(v);
          else          Y0[(size_t)grow*128 + gcol] = v;
        } else {
          Y0[(size_t)grow*256 + gcol] = v;
        }
      }
    }
  }
}

// ---------- per-node attention scalars ----------
template<int C>
__global__ void k_attn(const float* __restrict__ xt, const float* __restrict__ att_s,
                       const float* __restrict__ att_d, float* __restrict__ asrc,
                       float* __restrict__ adst){
  int wv = threadIdx.x>>6, l = threadIdx.x&63;
  int n = blockIdx.x*4 + wv;
  if(n >= NE) return;
  const float* row = xt + (size_t)n*2*C;
  float s0,s1,d0,d1;
  if(C==64){
    float v0=row[l], v1=row[64+l];
    s0 = v0*att_s[l];    s1 = v1*att_s[64+l];
    d0 = v0*att_d[l];    d1 = v1*att_d[64+l];
  } else {
    float v0=row[l], v1=row[64+l], v2=row[128+l], v3=row[192+l];
    s0 = v0*att_s[l] + v1*att_s[64+l];
    s1 = v2*att_s[128+l] + v3*att_s[192+l];
    d0 = v0*att_d[l] + v1*att_d[64+l];
    d1 = v2*att_d[128+l] + v3*att_d[192+l];
  }
  for(int o=32;o;o>>=1){
    s0+=__shfl_xor(s0,o); s1+=__shfl_xor(s1,o);
    d0+=__shfl_xor(d0,o); d1+=__shfl_xor(d1,o);
  }
  if(l==0){ asrc[n*2]=s0; asrc[n*2+1]=s1; adst[n*2]=d0; adst[n*2+1]=d1; }
}

// ---------- gather-based GAT aggregation, online softmax, one wave per node ----------
template<int C, bool LK, bool OUTBF>
__global__ __launch_bounds__(256) void k_agg(const float* __restrict__ xt,
    const float* __restrict__ asrc, const float* __restrict__ adst,
    const float* __restrict__ aE, const int* __restrict__ row_start,
    const int* __restrict__ src_s, const int* __restrict__ rel_s,
    const float* __restrict__ bias, void* __restrict__ outv){
  constexpr int HC = 2*C;
  constexpr int NJ = HC/64;
  int wv = threadIdx.x>>6, l = threadIdx.x&63;
  int n = blockIdx.x*4 + wv;
  if(n >= NE) return;
  int b = row_start[n], e = row_start[n+1];
  int deg = e - b;
  float2 ad = *reinterpret_cast<const float2*>(&adst[n*2]);
  float sE0=0.f, sE1=0.f;
  for(int i=b;i<e;i++){
    float2 a = *reinterpret_cast<const float2*>(&aE[rel_s[i]*2]);
    sE0 += a.x; sE1 += a.y;
  }
  float invdeg = 1.f/fmaxf((float)deg, 1.f);
  float2 asn = *reinterpret_cast<const float2*>(&asrc[n*2]);
  float m0 = lrelu(asn.x + ad.x + sE0*invdeg);
  float m1 = lrelu(asn.y + ad.y + sE1*invdeg);
  float den0=1.f, den1=1.f;
  float acc[NJ];
  #pragma unroll
  for(int j=0;j<NJ;j++) acc[j] = xt[(size_t)n*HC + j*64 + l];
  for(int i=b;i<e;i++){
    int s = src_s[i], r = rel_s[i];
    float2 as = *reinterpret_cast<const float2*>(&asrc[s*2]);
    float2 ae = *reinterpret_cast<const float2*>(&aE[r*2]);
    float l0 = lrelu(as.x + ad.x + ae.x);
    float l1 = lrelu(as.y + ad.y + ae.y);
    float nm0 = fmaxf(m0,l0), nm1 = fmaxf(m1,l1);
    float sc0 = __expf(m0-nm0), sc1 = __expf(m1-nm1);
    float w0  = __expf(l0-nm0), w1  = __expf(l1-nm1);
    den0 = den0*sc0 + w0; den1 = den1*sc1 + w1;
    m0 = nm0; m1 = nm1;
    #pragma unroll
    for(int j=0;j<NJ;j++){
      float sc = ((j*64)/C == 0) ? sc0 : sc1;
      float w  = ((j*64)/C == 0) ? w0  : w1;
      acc[j] = acc[j]*sc + w * xt[(size_t)s*HC + j*64 + l];
    }
  }
  float i0 = 1.f/(den0 + 1e-16f), i1 = 1.f/(den1 + 1e-16f);
  #pragma unroll
  for(int j=0;j<NJ;j++){
    int comp = j*64 + l;
    float v = acc[j] * (((j*64)/C == 0) ? i0 : i1) + bias[comp];
    if(LK) v = lrelu(v);
    if(OUTBF) ((u16*)outv)[(size_t)n*HC + comp] = f2bf(v);
    else      ((float*)outv)[(size_t)n*HC + comp] = v;
  }
}

// ---------- head-mean + skip(bf16) + L2 normalize ----------
__global__ void k_combine(const float* __restrict__ out2, const u16* __restrict__ skip,
                          float* __restrict__ xf){
  int wv = threadIdx.x>>6, l = threadIdx.x&63;
  int n = blockIdx.x*4 + wv;
  if(n >= NE) return;
  float v0 = 0.5f*(out2[(size_t)n*256 + l]      + out2[(size_t)n*256 + 128 + l]) + bf2f(skip[(size_t)n*128 + l]);
  float v1 = 0.5f*(out2[(size_t)n*256 + 64 + l] + out2[(size_t)n*256 + 192 + l]) + bf2f(skip[(size_t)n*128 + 64 + l]);
  float ss = v0*v0 + v1*v1;
  for(int o=32;o;o>>=1) ss += __shfl_xor(ss,o);
  float inv = 1.f/fmaxf(sqrtf(ss), 1e-12f);
  xf[(size_t)n*128 + l]      = v0*inv;
  xf[(size_t)n*128 + 64 + l] = v1*inv;
}

__global__ void k_gather(const int* __restrict__ ei, const float* __restrict__ xf,
                         float* __restrict__ out){
  int wv = threadIdx.x>>6, l = threadIdx.x&63;
  int e = blockIdx.x*4 + wv;
  if(e >= EB) return;
  int i0 = ei[e], i1 = ei[EB + e];
  out[(size_t)e*128 + l]                     = xf[(size_t)i0*128 + l];
  out[(size_t)e*128 + 64 + l]                = xf[(size_t)i0*128 + 64 + l];
  out[(size_t)EB*128 + (size_t)e*128 + l]    = xf[(size_t)i1*128 + l];
  out[(size_t)EB*128 + (size_t)e*128 + 64+l] = xf[(size_t)i1*128 + 64 + l];
}

// ---------- edge_attr @ W_r.T via sparsity (exact f32) ----------
__global__ void k_attr(const float* __restrict__ ea, const float* __restrict__ Wrt,
                       float* __restrict__ out){
  int wv = threadIdx.x>>6, l = threadIdx.x&63;
  int e = blockIdx.x*4 + wv;
  if(e >= EB) return;
  const float* row = ea + (size_t)e*NR;
  float acc0=0.f, acc1=0.f;
  #pragma unroll
  for(int ch=0; ch<4; ch++){
    int idx = ch*64 + l;
    float v = (idx < NR) ? row[idx] : 0.f;
    unsigned long long mask = __ballot(v != 0.f);
    while(mask){
      int bit = __builtin_ctzll(mask);
      mask &= mask - 1;
      int r = ch*64 + bit;
      float vv = __shfl(v, bit);
      acc0 += vv * Wrt[r*128 + l];
      acc1 += vv * Wrt[r*128 + 64 + l];
    }
  }
  out[(size_t)e*128 + l]      = acc0;
  out[(size_t)e*128 + 64 + l] = acc1;
}

extern "C" void kernel_launch(void* const* d_in, const int* in_sizes, int n_in,
                              void* d_out, int out_size, void* d_ws, size_t ws_size,
                              hipStream_t stream){
  const int*   edge_index = (const int*)  d_in[0];
  const float* edge_attr  = (const float*)d_in[1];
  const int*   edge_data  = (const int*)  d_in[2];
  const float* ent_emb    = (const float*)d_in[3];
  const float* rel_emb    = (const float*)d_in[4];
  const float* W1     = (const float*)d_in[5];
  const float* We1    = (const float*)d_in[6];
  const float* att_s1 = (const float*)d_in[7];
  const float* att_d1 = (const float*)d_in[8];
  const float* att_e1 = (const float*)d_in[9];
  const float* b1     = (const float*)d_in[10];
  const float* W2     = (const float*)d_in[11];
  const float* We2    = (const float*)d_in[12];
  const float* att_s2 = (const float*)d_in[13];
  const float* att_d2 = (const float*)d_in[14];
  const float* att_e2 = (const float*)d_in[15];
  const float* b2     = (const float*)d_in[16];
  const float* W_skip = (const float*)d_in[17];
  const float* W_r    = (const float*)d_in[18];
  float* out = (float*)d_out;

  char* ws = (char*)d_ws;
  size_t off = 0;
  auto alloc = [&](size_t bytes){ void* p = ws + off; off += (bytes + 255) & ~(size_t)255; return p; };
  int*   cnt       = (int*)  alloc((size_t)NE*4);
  int*   row_start = (int*)  alloc((size_t)(NE+1)*4);
  int*   src_s     = (int*)  alloc((size_t)EF*4);
  int*   rel_s     = (int*)  alloc((size_t)EF*4);
  float* vecE1     = (float*)alloc(128*2*4);
  float* vecE2     = (float*)alloc(128*2*4);
  float* aE1       = (float*)alloc(NR*2*4);
  float* aE2       = (float*)alloc(NR*2*4);
  float* asrc1     = (float*)alloc((size_t)NE*2*4);
  float* adst1     = (float*)alloc((size_t)NE*2*4);
  float* asrc2     = (float*)alloc((size_t)NE*2*4);
  float* adst2     = (float*)alloc((size_t)NE*2*4);
  u16*   WT1s      = (u16*)  alloc(256*128*2);
  u16*   WT2      = (u16*)  alloc(256*128*2);
  float* Wrt       = (float*)alloc(NR*128*4);
  float* xt1       = (float*)alloc((size_t)NE*128*4);
  u16*   skip      = (u16*)  alloc((size_t)NE*128*2);   // bf16
  u16*   h1        = (u16*)  alloc((size_t)NE*128*2);   // bf16
  float* xf = xt1;   // xt1 dead after agg1; reuse for normalized x
  // d_out doubles as scratch for the big [N,256] buffers; both dead before final writes.
  float* xt2  = out;                        // [NE*256]
  float* out2 = out + (size_t)NE*256;       // next [NE*256]

  hipMemsetAsync(cnt, 0, (size_t)NE*4, stream);
  k_count<<<(EF+255)/256, 256, 0, stream>>>(edge_data, cnt);
  k_scan<<<1, 1024, 0, stream>>>(cnt, row_start);
  hipMemsetAsync(cnt, 0, (size_t)NE*4, stream);
  k_fill<<<(EF+255)/256, 256, 0, stream>>>(edge_data, row_start, cnt, src_s, rel_s);
  k_vecE<<<1, 256, 0, stream>>>(We1, att_e1, We2, att_e2, vecE1, vecE2);
  k_aE<<<NR, 64, 0, stream>>>(rel_emb, vecE1, vecE2, aE1, aE2);
  k_prep<<<512, 128, 0, stream>>>(W1, W_skip, W2, WT1s, WT2);

  dim3 gg((NE+63)/64, 4);
  // layer 1 GEMM fused with skip-GEMM: [xt1 | skip] = ent_emb @ [W1 | W_skip^T]
  k_mgemm<false, true><<<gg, 256, 0, stream>>>(ent_emb, WT1s, xt1, skip, NE);
  k_attn<64><<<(NE+3)/4, 256, 0, stream>>>(xt1, att_s1, att_d1, asrc1, adst1);
  k_agg<64, true, true><<<(NE+3)/4, 256, 0, stream>>>(xt1, asrc1, adst1, aE1, row_start, src_s, rel_s, b1, h1);

  k_mgemm<true, false><<<gg, 256, 0, stream>>>(h1, WT2, xt2, nullptr, NE);
  k_attn<128><<<(NE+3)/4, 256, 0, stream>>>(xt2, att_s2, att_d2, asrc2, adst2);
  k_agg<128, false, false><<<(NE+3)/4, 256, 0, stream>>>(xt2, asrc2, adst2, aE2, row_start, src_s, rel_s, b2, out2);

  k_combine<<<(NE+3)/4, 256, 0, stream>>>(out2, skip, xf);

  k_tr<<<(128*NR+255)/256, 256, 0, stream>>>(W_r, Wrt, 128, NR);
  k_gather<<<(EB+3)/4, 256, 0, stream>>>(edge_index, xf, out);
  k_attr<<<(EB+3)/4, 256, 0, stream>>>(edge_attr, Wrt, out + (size_t)2*EB*128);
}

// Round 4
// 492.032 us; speedup vs baseline: 1.4910x; 1.1686x over previous
//
#include <hip/hip_runtime.h>

#define NE 50000      // N_ENT
#define NR 200        // N_REL
#define EF 300000     // E_FULL
#define EB 80000      // E_BATCH
#define NEG 0.2f
#define NINF (-1e30f)

typedef unsigned short u16;
typedef unsigned int u32;
typedef u16 u16x8 __attribute__((ext_vector_type(8)));
typedef __bf16 bf16x8 __attribute__((ext_vector_type(8)));
typedef float f32x4 __attribute__((ext_vector_type(4)));

__device__ __forceinline__ float lrelu(float x){ return x >= 0.f ? x : NEG*x; }
__device__ __forceinline__ u16 f2bf(float f){
  unsigned u = __float_as_uint(f);
  u = (u + 0x7FFFu + ((u >> 16) & 1u)) >> 16;   // RNE
  return (u16)u;
}
__device__ __forceinline__ float bf2f(u16 u){ return __uint_as_float(((unsigned)u) << 16); }
__device__ __forceinline__ float bflo(u32 p){ return __uint_as_float(p << 16); }
__device__ __forceinline__ float bfhi(u32 p){ return __uint_as_float(p & 0xFFFF0000u); }

// ---------- CSR build ----------
__global__ void k_count(const int* __restrict__ edge_data, int* __restrict__ cnt){
  int e = blockIdx.x*blockDim.x + threadIdx.x;
  if(e < EF) atomicAdd(&cnt[edge_data[2*EF + e]], 1);
}

__global__ void k_scan(const int* __restrict__ cnt, int* __restrict__ row_start){
  __shared__ int wsum[16];
  __shared__ int s_run;
  int tid = threadIdx.x;          // 1024
  int lane = tid & 63, wv = tid >> 6;
  if(tid==0) s_run = 0;
  __syncthreads();
  const int CH = 4096;
  const int nch = (NE + CH - 1)/CH;  // 13
  for(int c=0;c<nch;c++){
    int base = c*CH + tid*4;
    int v0 = base   < NE ? cnt[base]   : 0;
    int v1 = base+1 < NE ? cnt[base+1] : 0;
    int v2 = base+2 < NE ? cnt[base+2] : 0;
    int v3 = base+3 < NE ? cnt[base+3] : 0;
    int tsum = v0+v1+v2+v3;
    int x = tsum;
    #pragma unroll
    for(int o=1;o<64;o<<=1){
      int y = __shfl_up(x, o);
      if(lane >= o) x += y;
    }
    if(lane==63) wsum[wv] = x;
    __syncthreads();
    if(wv==0 && lane<16){
      int w = wsum[lane];
      #pragma unroll
      for(int o=1;o<16;o<<=1){
        int y = __shfl_up(w, o);
        if(lane>=o) w += y;
      }
      wsum[lane] = w;
    }
    __syncthreads();
    int woff = (wv>0) ? wsum[wv-1] : 0;
    int excl = s_run + woff + x - tsum;
    if(base   < NE) row_start[base]   = excl;
    if(base+1 < NE) row_start[base+1] = excl + v0;
    if(base+2 < NE) row_start[base+2] = excl + v0+v1;
    if(base+3 < NE) row_start[base+3] = excl + v0+v1+v2;
    __syncthreads();
    if(tid==1023) s_run += wsum[15];
    __syncthreads();
  }
  if(tid==0) row_start[NE] = s_run;
}

__global__ void k_fill(const int* __restrict__ edge_data, const int* __restrict__ row_start,
                       int* __restrict__ cnt, int* __restrict__ src_s, int* __restrict__ rel_s){
  int e = blockIdx.x*blockDim.x + threadIdx.x;
  if(e < EF){
    int s = edge_data[e], r = edge_data[EF+e], d = edge_data[2*EF+e];
    int pos = row_start[d] + atomicAdd(&cnt[d], 1);
    src_s[pos] = s; rel_s[pos] = r;
  }
}

// ---------- tiny precomputes ----------
__global__ void k_vecE(const float* __restrict__ We1, const float* __restrict__ ae1,
                       const float* __restrict__ We2, const float* __restrict__ ae2,
                       float* __restrict__ vecE1, float* __restrict__ vecE2){
  int t = threadIdx.x;           // 256
  int d = t>>1, h = t&1;
  float s1 = 0.f;
  for(int c=0;c<64;c++)  s1 += We1[d*128 + h*64  + c]*ae1[h*64  + c];
  vecE1[d*2+h] = s1;
  float s2 = 0.f;
  for(int c=0;c<128;c++) s2 += We2[d*256 + h*128 + c]*ae2[h*128 + c];
  vecE2[d*2+h] = s2;
}

__global__ void k_aE(const float* __restrict__ rel_emb, const float* __restrict__ vecE1,
                     const float* __restrict__ vecE2, float* __restrict__ aE1, float* __restrict__ aE2){
  int r = blockIdx.x, l = threadIdx.x;  // 64 threads
  float re0 = rel_emb[r*128 + l], re1 = rel_emb[r*128 + 64 + l];
  float a10 = re0*vecE1[l*2+0] + re1*vecE1[(64+l)*2+0];
  float a11 = re0*vecE1[l*2+1] + re1*vecE1[(64+l)*2+1];
  float a20 = re0*vecE2[l*2+0] + re1*vecE2[(64+l)*2+0];
  float a21 = re0*vecE2[l*2+1] + re1*vecE2[(64+l)*2+1];
  for(int o=32;o;o>>=1){
    a10 += __shfl_xor(a10,o); a11 += __shfl_xor(a11,o);
    a20 += __shfl_xor(a20,o); a21 += __shfl_xor(a21,o);
  }
  if(l==0){ aE1[r*2]=a10; aE1[r*2+1]=a11; aE2[r*2]=a20; aE2[r*2+1]=a21; }
}

__global__ void k_tr(const float* __restrict__ A, float* __restrict__ At, int R, int C){
  int t = blockIdx.x*blockDim.x + threadIdx.x;
  if(t < R*C){ int r = t / C, c = t % C; At[c*R + r] = A[t]; }
}

// builds WT1s[256][128] = [W1^T ; W_skip] bf16, WT2[256][128] = W2^T bf16
__global__ void k_prep(const float* __restrict__ W1, const float* __restrict__ Wsk,
                       const float* __restrict__ W2, u16* __restrict__ WT1s, u16* __restrict__ WT2){
  int r = blockIdx.x, k = threadIdx.x;   // 512 x 128
  if(r < 128)       WT1s[r*128+k] = f2bf(W1[k*128 + r]);
  else if(r < 256)  WT1s[r*128+k] = f2bf(Wsk[(r-128)*128 + k]);
  else              WT2[(r-256)*128+k] = f2bf(W2[k*256 + (r-256)]);
}

// ---------- MFMA GEMM: Y[N,256] = X[N,128] @ WT^T; A staged once, 4 B-tiles looped.
// XBF: X bf16 else f32. SPLIT: cols<128 -> Y0 bf16 stride 128, cols>=128 -> Yb bf16 stride 128;
// else all 256 cols -> Y0 bf16 stride 256.
template<bool XBF, bool SPLIT>
__global__ __launch_bounds__(256) void k_mgemm(const void* __restrict__ Xv,
    const u16* __restrict__ WT, u16* __restrict__ Y0, u16* __restrict__ Yb, int Nrows){
  __shared__ u16 As[64*128];   // [row][k], 16B chunk kc stored at kc ^ (row&7)
  __shared__ u16 Bs[64*128];
  int n0 = blockIdx.x*64;
  int t  = threadIdx.x;
  // ---- stage A (64 rows x 128 k) ----
  #pragma unroll
  for(int i=0;i<4;i++){
    int c = i*256 + t;            // chunk 0..1023
    int row = c >> 4, kc = c & 15;
    u16x8 pk;
    if(XBF){
      const u16* Xb = (const u16*)Xv;
      if(n0+row < Nrows) pk = *reinterpret_cast<const u16x8*>(&Xb[(size_t)(n0+row)*128 + kc*8]);
      else               pk = (u16x8)(u16)0;
    } else {
      const float* Xf = (const float*)Xv;
      float4 v0 = make_float4(0,0,0,0), v1 = v0;
      if(n0+row < Nrows){
        const float4* p = reinterpret_cast<const float4*>(&Xf[(size_t)(n0+row)*128 + kc*8]);
        v0 = p[0]; v1 = p[1];
      }
      pk[0]=f2bf(v0.x); pk[1]=f2bf(v0.y); pk[2]=f2bf(v0.z); pk[3]=f2bf(v0.w);
      pk[4]=f2bf(v1.x); pk[5]=f2bf(v1.y); pk[6]=f2bf(v1.z); pk[7]=f2bf(v1.w);
    }
    *reinterpret_cast<u16x8*>(&As[row*128 + ((kc ^ (row&7))<<3)]) = pk;
  }
  int l = t & 63, w = t >> 6;
  int wr = w >> 1, wc = w & 1;
  int lr = l & 15, kg = l >> 4;
  const bf16x8* asp = reinterpret_cast<const bf16x8*>(As);
  const bf16x8* bsp = reinterpret_cast<const bf16x8*>(Bs);
  for(int cbi=0; cbi<4; cbi++){
    int cb = cbi*64;
    // ---- stage B tile ----
    #pragma unroll
    for(int i=0;i<4;i++){
      int c = i*256 + t;
      int row = c >> 4, kc = c & 15;
      u16x8 pk = *reinterpret_cast<const u16x8*>(&WT[(size_t)(cb+row)*128 + kc*8]);
      *reinterpret_cast<u16x8*>(&Bs[row*128 + ((kc ^ (row&7))<<3)]) = pk;
    }
    __syncthreads();
    f32x4 acc[2][2] = {};
    #pragma unroll
    for(int kk=0; kk<4; kk++){
      bf16x8 a[2], b[2];
      #pragma unroll
      for(int m=0;m<2;m++){
        int fr = wr*32 + m*16 + lr;
        a[m] = asp[fr*16 + ((kk*4 + kg) ^ (fr&7))];
      }
      #pragma unroll
      for(int n=0;n<2;n++){
        int fc = wc*32 + n*16 + lr;
        b[n] = bsp[fc*16 + ((kk*4 + kg) ^ (fc&7))];
      }
      #pragma unroll
      for(int m=0;m<2;m++)
        #pragma unroll
        for(int n=0;n<2;n++)
          acc[m][n] = __builtin_amdgcn_mfma_f32_16x16x32_bf16(a[m], b[n], acc[m][n], 0, 0, 0);
    }
    // ---- epilogue: D lane map col=l&15, row=(l>>4)*4+r ----
    #pragma unroll
    for(int m=0;m<2;m++){
      #pragma unroll
      for(int r=0;r<4;r++){
        int grow = n0 + wr*32 + m*16 + kg*4 + r;
        if(grow < Nrows){
          #pragma unroll
          for(int n=0;n<2;n++){
            int gcol = cb + wc*32 + n*16 + lr;
            u16 v = f2bf(acc[m][n][r]);
            if(SPLIT){
              if(cb >= 128) Yb[(size_t)grow*128 + (gcol-128)] = v;
              else          Y0[(size_t)grow*128 + gcol] = v;
            } else {
              Y0[(size_t)grow*256 + gcol] = v;
            }
          }
        }
      }
    }
    __syncthreads();   // protect Bs before next stage
  }
}

// ---------- per-node attention scalars (xt bf16, paired loads) ----------
template<int C>
__global__ void k_attn(const u16* __restrict__ xt, const float* __restrict__ att_s,
                       const float* __restrict__ att_d, float* __restrict__ asrc,
                       float* __restrict__ adst){
  int wv = threadIdx.x>>6, l = threadIdx.x&63;
  int n = blockIdx.x*4 + wv;
  if(n >= NE) return;
  const u32* row = reinterpret_cast<const u32*>(xt) + (size_t)n*C;  // C pairs
  if(C==64){
    u32 p = row[l];
    float x0 = bflo(p), x1 = bfhi(p);
    float sl = x0*att_s[2*l] + x1*att_s[2*l+1];
    float dl = x0*att_d[2*l] + x1*att_d[2*l+1];
    #pragma unroll
    for(int o=16;o;o>>=1){ sl += __shfl_xor(sl,o); dl += __shfl_xor(dl,o); }
    if(l==0){  asrc[n*2]   = sl; adst[n*2]   = dl; }
    if(l==32){ asrc[n*2+1] = sl; adst[n*2+1] = dl; }
  } else {
    u32 p0 = row[l], p1 = row[64+l];
    float x00 = bflo(p0), x01 = bfhi(p0), x10 = bflo(p1), x11 = bfhi(p1);
    float s0 = x00*att_s[2*l]     + x01*att_s[2*l+1];
    float s1 = x10*att_s[128+2*l] + x11*att_s[128+2*l+1];
    float d0 = x00*att_d[2*l]     + x01*att_d[2*l+1];
    float d1 = x10*att_d[128+2*l] + x11*att_d[128+2*l+1];
    #pragma unroll
    for(int o=32;o;o>>=1){
      s0+=__shfl_xor(s0,o); s1+=__shfl_xor(s1,o);
      d0+=__shfl_xor(d0,o); d1+=__shfl_xor(d1,o);
    }
    if(l==0){ asrc[n*2]=s0; asrc[n*2+1]=s1; adst[n*2]=d0; adst[n*2+1]=d1; }
  }
}

// ---------- single-pass online-softmax GAT aggregation, one wave per node ----------
// xt: bf16 [NE][2C]; self-loop applied as final online update (sE accumulated in-loop).
template<int C, bool LK, bool OUTBF>
__global__ __launch_bounds__(256) void k_agg(const u16* __restrict__ xt,
    const float* __restrict__ asrc, const float* __restrict__ adst,
    const float* __restrict__ aE, const int* __restrict__ row_start,
    const int* __restrict__ src_s, const int* __restrict__ rel_s,
    const float* __restrict__ bias, void* __restrict__ outv){
  constexpr int NP = C/64;     // uint-pair loads per 64-lane wave
  __shared__ float2 sAE[NR];
  int tid = threadIdx.x;
  for(int i=tid; i<NR; i+=256) sAE[i] = reinterpret_cast<const float2*>(aE)[i];
  __syncthreads();
  int wv = tid>>6, l = tid&63;
  int n = blockIdx.x*4 + wv;
  if(n >= NE) return;
  int b = row_start[n], e = row_start[n+1];
  int deg = e - b;
  float2 ad  = *reinterpret_cast<const float2*>(&adst[n*2]);
  float2 asn = *reinterpret_cast<const float2*>(&asrc[n*2]);
  const u32* xtu = reinterpret_cast<const u32*>(xt);
  float m0=NINF, m1=NINF, den0=0.f, den1=0.f, sE0=0.f, sE1=0.f;
  float acc[NP][2];
  #pragma unroll
  for(int j=0;j<NP;j++){ acc[j][0]=0.f; acc[j][1]=0.f; }
  for(int i=b;i<e;i++){
    int s = src_s[i], r = rel_s[i];
    float2 as = *reinterpret_cast<const float2*>(&asrc[s*2]);
    float2 ae = sAE[r];
    sE0 += ae.x; sE1 += ae.y;
    float l0 = lrelu(as.x + ad.x + ae.x);
    float l1 = lrelu(as.y + ad.y + ae.y);
    float nm0 = fmaxf(m0,l0), nm1 = fmaxf(m1,l1);
    float sc0 = __expf(m0-nm0), sc1 = __expf(m1-nm1);
    float w0  = __expf(l0-nm0), w1  = __expf(l1-nm1);
    den0 = den0*sc0 + w0; den1 = den1*sc1 + w1;
    m0 = nm0; m1 = nm1;
    #pragma unroll
    for(int j=0;j<NP;j++){
      u32 p = xtu[(size_t)s*C + j*64 + l];
      float sc, w;
      if(C==64){ sc = (l<32)?sc0:sc1; w = (l<32)?w0:w1; }
      else     { sc = (j==0)?sc0:sc1; w = (j==0)?w0:w1; }
      acc[j][0] = acc[j][0]*sc + w*bflo(p);
      acc[j][1] = acc[j][1]*sc + w*bfhi(p);
    }
  }
  // self-loop as final online update (ea_loop = mean of incoming aE; 0 if deg==0)
  {
    float invdeg = 1.f/fmaxf((float)deg, 1.f);
    float l0 = lrelu(asn.x + ad.x + sE0*invdeg);
    float l1 = lrelu(asn.y + ad.y + sE1*invdeg);
    float nm0 = fmaxf(m0,l0), nm1 = fmaxf(m1,l1);
    float sc0 = __expf(m0-nm0), sc1 = __expf(m1-nm1);
    float w0  = __expf(l0-nm0), w1  = __expf(l1-nm1);
    den0 = den0*sc0 + w0; den1 = den1*sc1 + w1;
    #pragma unroll
    for(int j=0;j<NP;j++){
      u32 p = xtu[(size_t)n*C + j*64 + l];
      float sc, w;
      if(C==64){ sc = (l<32)?sc0:sc1; w = (l<32)?w0:w1; }
      else     { sc = (j==0)?sc0:sc1; w = (j==0)?w0:w1; }
      acc[j][0] = acc[j][0]*sc + w*bflo(p);
      acc[j][1] = acc[j][1]*sc + w*bfhi(p);
    }
  }
  float i0 = 1.f/(den0 + 1e-16f), i1 = 1.f/(den1 + 1e-16f);
  #pragma unroll
  for(int j=0;j<NP;j++){
    float ih;
    if(C==64) ih = (l<32)?i0:i1; else ih = (j==0)?i0:i1;
    float2 bp = reinterpret_cast<const float2*>(bias)[j*64 + l];
    float v0 = acc[j][0]*ih + bp.x;
    float v1 = acc[j][1]*ih + bp.y;
    if(LK){ v0 = lrelu(v0); v1 = lrelu(v1); }
    if(OUTBF){
      ((u32*)outv)[(size_t)n*C + j*64 + l] = (u32)f2bf(v0) | ((u32)f2bf(v1)<<16);
    } else {
      reinterpret_cast<float2*>(outv)[(size_t)n*(C) + j*64 + l] = make_float2(v0, v1);
    }
  }
}

// ---------- head-mean + skip(bf16) + L2 normalize -> xf bf16 ----------
__global__ void k_combine(const float* __restrict__ out2, const u16* __restrict__ skip,
                          u16* __restrict__ xf){
  int wv = threadIdx.x>>6, l = threadIdx.x&63;
  int n = blockIdx.x*4 + wv;
  if(n >= NE) return;
  const float2* o2 = reinterpret_cast<const float2*>(out2) + (size_t)n*128;
  float2 a0 = o2[l], a1 = o2[64+l];                 // comps (2l,2l+1) heads 0 and 1
  u32 sp = reinterpret_cast<const u32*>(skip)[(size_t)n*64 + l];
  float v0 = 0.5f*(a0.x + a1.x) + bflo(sp);
  float v1 = 0.5f*(a0.y + a1.y) + bfhi(sp);
  float ss = v0*v0 + v1*v1;
  for(int o=32;o;o>>=1) ss += __shfl_xor(ss,o);
  float inv = 1.f/fmaxf(sqrtf(ss), 1e-12f);
  reinterpret_cast<u32*>(xf)[(size_t)n*64 + l] = (u32)f2bf(v0*inv) | ((u32)f2bf(v1*inv)<<16);
}

__global__ void k_gather(const int* __restrict__ ei, const u16* __restrict__ xf,
                         float* __restrict__ out){
  int wv = threadIdx.x>>6, l = threadIdx.x&63;
  int e = blockIdx.x*4 + wv;
  if(e >= EB) return;
  int i0 = ei[e], i1 = ei[EB + e];
  u32 p0 = reinterpret_cast<const u32*>(xf)[(size_t)i0*64 + l];
  u32 p1 = reinterpret_cast<const u32*>(xf)[(size_t)i1*64 + l];
  reinterpret_cast<float2*>(out)[(size_t)e*64 + l] = make_float2(bflo(p0), bfhi(p0));
  reinterpret_cast<float2*>(out + (size_t)EB*128)[(size_t)e*64 + l] = make_float2(bflo(p1), bfhi(p1));
}

// ---------- edge_attr @ W_r.T via sparsity (exact f32) ----------
__global__ void k_attr(const float* __restrict__ ea, const float* __restrict__ Wrt,
                       float* __restrict__ out){
  int wv = threadIdx.x>>6, l = threadIdx.x&63;
  int e = blockIdx.x*4 + wv;
  if(e >= EB) return;
  const float* row = ea + (size_t)e*NR;
  float acc0=0.f, acc1=0.f;
  #pragma unroll
  for(int ch=0; ch<4; ch++){
    int idx = ch*64 + l;
    float v = (idx < NR) ? row[idx] : 0.f;
    unsigned long long mask = __ballot(v != 0.f);
    while(mask){
      int bit = __builtin_ctzll(mask);
      mask &= mask - 1;
      int r = ch*64 + bit;
      float vv = __shfl(v, bit);
      acc0 += vv * Wrt[r*128 + l];
      acc1 += vv * Wrt[r*128 + 64 + l];
    }
  }
  out[(size_t)e*128 + l]      = acc0;
  out[(size_t)e*128 + 64 + l] = acc1;
}

extern "C" void kernel_launch(void* const* d_in, const int* in_sizes, int n_in,
                              void* d_out, int out_size, void* d_ws, size_t ws_size,
                              hipStream_t stream){
  const int*   edge_index = (const int*)  d_in[0];
  const float* edge_attr  = (const float*)d_in[1];
  const int*   edge_data  = (const int*)  d_in[2];
  const float* ent_emb    = (const float*)d_in[3];
  const float* rel_emb    = (const float*)d_in[4];
  const float* W1     = (const float*)d_in[5];
  const float* att_s1 = (const float*)d_in[7];
  const float* att_d1 = (const float*)d_in[8];
  const float* att_e1 = (const float*)d_in[9];
  const float* b1     = (const float*)d_in[10];
  const float* W2     = (const float*)d_in[11];
  const float* We1    = (const float*)d_in[6];
  const float* We2    = (const float*)d_in[12];
  const float* att_s2 = (const float*)d_in[13];
  const float* att_d2 = (const float*)d_in[14];
  const float* att_e2 = (const float*)d_in[15];
  const float* b2     = (const float*)d_in[16];
  const float* W_skip = (const float*)d_in[17];
  const float* W_r    = (const float*)d_in[18];
  float* out = (float*)d_out;

  char* ws = (char*)d_ws;
  size_t off = 0;
  auto alloc = [&](size_t bytes){ void* p = ws + off; off += (bytes + 255) & ~(size_t)255; return p; };
  int*   cnt       = (int*)  alloc((size_t)NE*4);
  int*   row_start = (int*)  alloc((size_t)(NE+1)*4);
  int*   src_s     = (int*)  alloc((size_t)EF*4);
  int*   rel_s     = (int*)  alloc((size_t)EF*4);
  float* vecE1     = (float*)alloc(128*2*4);
  float* vecE2     = (float*)alloc(128*2*4);
  float* aE1       = (float*)alloc(NR*2*4);
  float* aE2       = (float*)alloc(NR*2*4);
  float* asrc1     = (float*)alloc((size_t)NE*2*4);
  float* adst1     = (float*)alloc((size_t)NE*2*4);
  float* asrc2     = (float*)alloc((size_t)NE*2*4);
  float* adst2     = (float*)alloc((size_t)NE*2*4);
  u16*   WT1s      = (u16*)  alloc(256*128*2);
  u16*   WT2       = (u16*)  alloc(256*128*2);
  float* Wrt       = (float*)alloc(NR*128*4);
  u16*   xt1       = (u16*)  alloc((size_t)NE*128*2);   // bf16; reused as xf after agg1
  u16*   skip      = (u16*)  alloc((size_t)NE*128*2);   // bf16
  u16*   h1        = (u16*)  alloc((size_t)NE*128*2);   // bf16
  u16*   xf = xt1;
  // d_out doubles as scratch: xt2 bf16 [NE][256] then out2 f32 [NE][256]; both dead
  // before k_gather/k_attr overwrite those byte ranges (stream-ordered).
  u16*   xt2  = (u16*)out;                              // 25.6 MB
  float* out2 = out + (size_t)NE*128;                   // floats [6.4M, 19.2M)

  hipMemsetAsync(cnt, 0, (size_t)NE*4, stream);
  k_count<<<(EF+255)/256, 256, 0, stream>>>(edge_data, cnt);
  k_scan<<<1, 1024, 0, stream>>>(cnt, row_start);
  hipMemsetAsync(cnt, 0, (size_t)NE*4, stream);
  k_fill<<<(EF+255)/256, 256, 0, stream>>>(edge_data, row_start, cnt, src_s, rel_s);
  k_vecE<<<1, 256, 0, stream>>>(We1, att_e1, We2, att_e2, vecE1, vecE2);
  k_aE<<<NR, 64, 0, stream>>>(rel_emb, vecE1, vecE2, aE1, aE2);
  k_prep<<<512, 128, 0, stream>>>(W1, W_skip, W2, WT1s, WT2);
  k_tr<<<(128*NR+255)/256, 256, 0, stream>>>(W_r, Wrt, 128, NR);

  int gg = (NE+63)/64;
  // layer 1 GEMM fused with skip-GEMM: [xt1 | skip] = ent_emb @ [W1 | W_skip^T]
  k_mgemm<false, true><<<gg, 256, 0, stream>>>(ent_emb, WT1s, xt1, skip, NE);
  k_attn<64><<<(NE+3)/4, 256, 0, stream>>>(xt1, att_s1, att_d1, asrc1, adst1);
  k_agg<64, true, true><<<(NE+3)/4, 256, 0, stream>>>(xt1, asrc1, adst1, aE1, row_start, src_s, rel_s, b1, h1);

  k_mgemm<true, false><<<gg, 256, 0, stream>>>(h1, WT2, xt2, nullptr, NE);
  k_attn<128><<<(NE+3)/4, 256, 0, stream>>>(xt2, att_s2, att_d2, asrc2, adst2);
  k_agg<128, false, false><<<(NE+3)/4, 256, 0, stream>>>(xt2, asrc2, adst2, aE2, row_start, src_s, rel_s, b2, out2);

  k_combine<<<(NE+3)/4, 256, 0, stream>>>(out2, skip, xf);

  k_gather<<<(EB+3)/4, 256, 0, stream>>>(edge_index, xf, out);
  k_attr<<<(EB+3)/4, 256, 0, stream>>>(edge_attr, Wrt, out + (size_t)2*EB*128);
}